// Round 1
// baseline (2672.271 us; speedup 1.0000x reference)
//
#include <hip/hip_runtime.h>
#include <cmath>

// Tile geometry for the fp32 GEMM
#define TM 128
#define TN 128
#define TK 16
#define PAD 4  // +4 floats keeps float4 alignment (132*4B % 16 == 0), breaks bank aliasing

// proj[g][m][u] = sum_d x[row(m)][d] * W_g[d][u] + bias_g[u]
// row(m) = (m / Tc)*T + t0 + (m % Tc)   (chunked over time)
__global__ __launch_bounds__(256)
void bru_gemm3(const float* __restrict__ x,
               const float* __restrict__ wz, const float* __restrict__ wr,
               const float* __restrict__ wh,
               const float* __restrict__ bz, const float* __restrict__ br,
               const float* __restrict__ bh,
               float* __restrict__ proj,
               int T, int D, int U, int Tc, int t0, int Mc)
{
    __shared__ float As[TK][TM + PAD];
    __shared__ float Bs[TK][TN + PAD];

    const int g = blockIdx.z;
    const float* __restrict__ W    = (g == 0) ? wz : (g == 1) ? wr : wh;
    const float* __restrict__ bias = (g == 0) ? bz : (g == 1) ? br : bh;

    const int m0 = blockIdx.x * TM;
    const int n0 = blockIdx.y * TN;
    const int tid = threadIdx.x;

    // A staging: each thread loads 8 consecutive k of one m-row (two float4)
    const int a_m = tid >> 1;            // 0..127
    const int a_k = (tid & 1) * 8;       // 0 or 8
    const int gm  = m0 + a_m;
    const long a_row = (long)(gm / Tc) * T + t0 + (gm % Tc);
    const float* a_src = x + a_row * (long)D + a_k;

    // B staging: 16 k-rows x 128 u; each thread loads 2 float4
    const int b_k = tid >> 4;            // 0..15
    const int b_u = (tid & 15) * 4;      // 0..60
    const float* b_src = W + (long)b_k * U + n0 + b_u;

    // 8x8 per-thread microtile
    const int tm = (tid >> 4) * 8;
    const int tn = (tid & 15) * 8;

    float acc[8][8];
    #pragma unroll
    for (int i = 0; i < 8; ++i)
        #pragma unroll
        for (int j = 0; j < 8; ++j) acc[i][j] = 0.f;

    for (int k0 = 0; k0 < D; k0 += TK) {
        float4 av0 = *(const float4*)(a_src + k0);
        float4 av1 = *(const float4*)(a_src + k0 + 4);
        float4 bv0 = *(const float4*)(b_src + (long)k0 * U);
        float4 bv1 = *(const float4*)(b_src + (long)k0 * U + 64);

        __syncthreads();  // previous iteration's readers done
        As[a_k + 0][a_m] = av0.x; As[a_k + 1][a_m] = av0.y;
        As[a_k + 2][a_m] = av0.z; As[a_k + 3][a_m] = av0.w;
        As[a_k + 4][a_m] = av1.x; As[a_k + 5][a_m] = av1.y;
        As[a_k + 6][a_m] = av1.z; As[a_k + 7][a_m] = av1.w;
        *(float4*)&Bs[b_k][b_u]      = bv0;
        *(float4*)&Bs[b_k][b_u + 64] = bv1;
        __syncthreads();

        #pragma unroll
        for (int k = 0; k < TK; ++k) {
            float4 a0 = *(const float4*)&As[k][tm];
            float4 a1 = *(const float4*)&As[k][tm + 4];
            float4 q0 = *(const float4*)&Bs[k][tn];
            float4 q1 = *(const float4*)&Bs[k][tn + 4];
            float ar[8] = {a0.x, a0.y, a0.z, a0.w, a1.x, a1.y, a1.z, a1.w};
            float br_[8] = {q0.x, q0.y, q0.z, q0.w, q1.x, q1.y, q1.z, q1.w};
            #pragma unroll
            for (int i = 0; i < 8; ++i)
                #pragma unroll
                for (int j = 0; j < 8; ++j)
                    acc[i][j] = fmaf(ar[i], br_[j], acc[i][j]);
        }
    }

    // epilogue: add bias, store
    float bvreg[8];
    #pragma unroll
    for (int j = 0; j < 8; ++j) bvreg[j] = bias[n0 + tn + j];

    float* cbase = proj + (long)g * Mc * U;
    #pragma unroll
    for (int i = 0; i < 8; ++i) {
        float* crow = cbase + (long)(m0 + tm + i) * U + n0 + tn;
        float4 v0, v1;
        v0.x = acc[i][0] + bvreg[0]; v0.y = acc[i][1] + bvreg[1];
        v0.z = acc[i][2] + bvreg[2]; v0.w = acc[i][3] + bvreg[3];
        v1.x = acc[i][4] + bvreg[4]; v1.y = acc[i][5] + bvreg[5];
        v1.z = acc[i][6] + bvreg[6]; v1.w = acc[i][7] + bvreg[7];
        *(float4*)(crow)     = v0;
        *(float4*)(crow + 4) = v1;
    }
}

// Scan: one thread per (b,u), private loop over the chunk's timesteps.
__global__ __launch_bounds__(256)
void bru_scan(const float* __restrict__ proj,  // [3][Mc][U]
              const float* __restrict__ mz, const float* __restrict__ mr,
              float* __restrict__ out,         // [B][T][U]
              float* __restrict__ hstate,      // [B*U]
              int B, int T, int U, int Tc, int t0, int Mc)
{
    const int idx = blockIdx.x * blockDim.x + threadIdx.x;  // b*U + u
    const int b = idx / U;
    const int u = idx - b * U;

    float h = (t0 == 0) ? 0.f : hstate[idx];
    const float vmz = mz[u];
    const float vmr = mr[u];

    const float* pz = proj + (long)b * Tc * U + u;
    const float* pr = pz + (long)Mc * U;
    const float* ph = pr + (long)Mc * U;
    float* po = out + ((long)b * T + t0) * U + u;

    // 1-deep software pipeline on the three loads
    float xz = pz[0], xr = pr[0], xh = ph[0];
    for (int t = 0; t < Tc; ++t) {
        float nxz = 0.f, nxr = 0.f, nxh = 0.f;
        if (t + 1 < Tc) {
            const long o = (long)(t + 1) * U;
            nxz = pz[o]; nxr = pr[o]; nxh = ph[o];
        }
        float r  = tanhf(xr + h * vmr) + 1.0f;
        float z  = 1.0f / (1.0f + __expf(-(xz + h * vmz)));
        float hh = tanhf(xh + r * h);
        h = (1.0f - z) * hh + z * h;
        po[(long)t * U] = h;
        xz = nxz; xr = nxr; xh = nxh;
    }
    hstate[idx] = h;
}

extern "C" void kernel_launch(void* const* d_in, const int* in_sizes, int n_in,
                              void* d_out, int out_size, void* d_ws, size_t ws_size,
                              hipStream_t stream)
{
    const float* x  = (const float*)d_in[0];
    const float* wz = (const float*)d_in[1];
    const float* wr = (const float*)d_in[2];
    const float* wh = (const float*)d_in[3];
    const float* mz = (const float*)d_in[4];
    const float* mr = (const float*)d_in[5];
    const float* bz = (const float*)d_in[6];
    const float* br = (const float*)d_in[7];
    const float* bh = (const float*)d_in[8];

    const int B = 64, T = 512, D = 1024, U = 1024;

    // ws layout: [h: B*U fp32][proj: 3 * B*Tc * U fp32]
    const size_t h_bytes = (size_t)B * U * sizeof(float);
    float* h_state = (float*)d_ws;
    float* proj = (float*)((char*)d_ws + h_bytes);

    int Tc = T;
    while (Tc > 2) {
        size_t need = h_bytes + 3ull * B * Tc * U * sizeof(float);
        if (need <= ws_size) break;
        Tc >>= 1;
    }

    for (int t0 = 0; t0 < T; t0 += Tc) {
        const int Mc = B * Tc;
        dim3 gg(Mc / TM, U / TN, 3);
        bru_gemm3<<<gg, 256, 0, stream>>>(x, wz, wr, wh, bz, br, bh, proj,
                                          T, D, U, Tc, t0, Mc);
        dim3 gs((B * U) / 256);
        bru_scan<<<gs, 256, 0, stream>>>(proj, mz, mr, (float*)d_out, h_state,
                                         B, T, U, Tc, t0, Mc);
    }
}

// Round 2
// 901.045 us; speedup vs baseline: 2.9657x; 2.9657x over previous
//
#include <hip/hip_runtime.h>
#include <cmath>

using bf16x8 = __attribute__((ext_vector_type(8))) short;
using f32x4  = __attribute__((ext_vector_type(4))) float;

// ---------- helpers ----------
__device__ __forceinline__ short f2bf_rne(float f) {
    union { float f; unsigned u; } a; a.f = f;
    unsigned r = a.u + 0x7fffu + ((a.u >> 16) & 1u);
    return (short)(r >> 16);
}
__device__ __forceinline__ float bf2f(short s) {
    union { unsigned u; float f; } a;
    a.u = ((unsigned)(unsigned short)s) << 16;
    return a.f;
}
__device__ __forceinline__ void gld16(void* lds, const void* g) {
    __builtin_amdgcn_global_load_lds(
        (const __attribute__((address_space(1))) unsigned int*)g,
        (__attribute__((address_space(3))) unsigned int*)lds, 16, 0, 0);
}

// Blob layout (shared by converts + GEMM staging):
// per (tile, ktile): 16384 shorts = 32KB: [hi: 8192][lo: 8192].
// hi slot (row, cb) at short idx row*64 + cb*8 holds elements
//   k = (cb ^ (row&7))*8 + j  (j=0..7) of that row — i.e. a pre-swizzled LDS image
//   so a linear global_load_lds produces XOR-swizzled LDS (conflict-free ds_read_b128).

// ---------- convert x -> A blobs (gathered chunk rows, hi/lo bf16) ----------
__global__ __launch_bounds__(256)
void bru_conv_a(const float* __restrict__ x, short* __restrict__ Ablob,
                int T, int D, int Tc, int t0, int nkt)
{
    const int gid  = blockIdx.x * 256 + threadIdx.x;   // one 16B group
    const int blob = gid >> 10;                        // 1024 groups per blob
    const int idx  = gid & 1023;
    const int row  = idx >> 3;
    const int cb   = idx & 7;
    const int mt   = blob / nkt;
    const int kt   = blob - mt * nkt;

    const int m  = mt * 128 + row;
    const int d0 = kt * 64 + ((cb ^ (row & 7)) << 3);
    const long xrow = (long)(m / Tc) * T + t0 + (m % Tc);
    const float* src = x + xrow * (long)D + d0;

    float v[8];
    *(float4*)&v[0] = *(const float4*)(src);
    *(float4*)&v[4] = *(const float4*)(src + 4);

    short hi[8], lo[8];
    #pragma unroll
    for (int j = 0; j < 8; ++j) {
        hi[j] = f2bf_rne(v[j]);
        lo[j] = f2bf_rne(v[j] - bf2f(hi[j]));
    }
    short* base = Ablob + (size_t)blob * 16384;
    *(bf16x8*)(base + row * 64 + cb * 8)        = *(bf16x8*)hi;
    *(bf16x8*)(base + 8192 + row * 64 + cb * 8) = *(bf16x8*)lo;
}

// ---------- convert W (3 gates) -> B blobs (transposed: row=u-col, k-contig) ----------
__global__ __launch_bounds__(256)
void bru_conv_w(const float* __restrict__ wz, const float* __restrict__ wr,
                const float* __restrict__ wh, short* __restrict__ Wblob,
                int D, int U, int nnt, int nkt)
{
    const int gid  = blockIdx.x * 256 + threadIdx.x;
    const int blob = gid >> 10;
    const int idx  = gid & 1023;
    const int row  = idx >> 3;     // u within 128-col tile
    const int cb   = idx & 7;

    const int per_gate = nnt * nkt;
    const int g    = blob / per_gate;
    const int rest = blob - g * per_gate;
    const int ut   = rest / nkt;
    const int kt   = rest - ut * nkt;

    const float* W = (g == 0) ? wz : (g == 1) ? wr : wh;
    const int d0 = kt * 64 + ((cb ^ (row & 7)) << 3);
    const int u  = ut * 128 + row;

    short hi[8], lo[8];
    #pragma unroll
    for (int j = 0; j < 8; ++j) {
        float v = W[(long)(d0 + j) * U + u];
        hi[j] = f2bf_rne(v);
        lo[j] = f2bf_rne(v - bf2f(hi[j]));
    }
    short* base = Wblob + (size_t)blob * 16384;
    *(bf16x8*)(base + row * 64 + cb * 8)        = *(bf16x8*)hi;
    *(bf16x8*)(base + 8192 + row * 64 + cb * 8) = *(bf16x8*)lo;
}

// ---------- split-precision bf16 MFMA GEMM ----------
// C[g][m][u] = sum_d A[m][d] * W_g[d][u] + bias_g[u], via hi*hi + hi*lo + lo*hi
__global__ __launch_bounds__(256, 2)
void bru_gemm_mfma(const short* __restrict__ Ablob, const short* __restrict__ Wblob,
                   const float* __restrict__ bz, const float* __restrict__ br,
                   const float* __restrict__ bh,
                   float* __restrict__ proj,
                   int nmt, int nkt, int U, int Mc)
{
    __shared__ short smem[32768];   // 64KB: A hi|lo (32KB), B hi|lo (32KB)

    const int ngrid = gridDim.x;
    const int bid   = blockIdx.x;
    // XCD chunk swizzle (ngrid % 8 == 0 always here)
    const int lid = (bid & 7) * (ngrid >> 3) + (bid >> 3);
    const int per_gate = nmt * 8;
    const int g  = lid / per_gate;
    const int r  = lid - g * per_gate;
    const int sb = r >> 6;                 // 8mt x 8nt superblocks
    const int wi = r & 63;
    const int mt = sb * 8 + (wi & 7);
    const int nt = wi >> 3;

    const int tid  = threadIdx.x;
    const int w    = tid >> 6;
    const int lane = tid & 63;
    const int wm   = w >> 1, wn = w & 1;   // 2x2 wave grid, each wave 64x64
    const int lane15 = lane & 15;
    const int lgrp   = lane >> 4;          // 0..3
    const int swz    = (lane & 7) << 4;

    const char* asrc = (const char*)(Ablob + (size_t)(mt * nkt) * 16384);
    const char* bsrc = (const char*)(Wblob + (size_t)((g * 8 + nt) * nkt) * 16384);
    char* sm = (char*)smem;

    // per-thread LDS byte bases for fragment reads
    int aoff[4], boff[4];
    #pragma unroll
    for (int f = 0; f < 4; ++f) {
        aoff[f] = (wm * 64 + f * 16 + lane15) * 128;
        boff[f] = (wn * 64 + f * 16 + lane15) * 128;
    }

    f32x4 acc[4][4];
    #pragma unroll
    for (int i = 0; i < 4; ++i)
        #pragma unroll
        for (int j = 0; j < 4; ++j) acc[i][j] = (f32x4)0.f;

    for (int kt = 0; kt < nkt; ++kt) {
        // stage 64KB: A blob (32KB) + B blob (32KB), linear -> pre-swizzled image
        const char* ab = asrc + (size_t)kt * 32768;
        const char* bb = bsrc + (size_t)kt * 32768;
        #pragma unroll
        for (int i = 0; i < 8; ++i) {
            const int loff = i * 4096 + w * 1024;
            gld16(sm + loff,         ab + loff + lane * 16);
            gld16(sm + 32768 + loff, bb + loff + lane * 16);
        }
        __syncthreads();   // compiler emits vmcnt(0) drain here

        #pragma unroll
        for (int kk = 0; kk < 2; ++kk) {
            const int col = ((kk << 6) | (lgrp << 4)) ^ swz;
            bf16x8 ah[4], al[4], bhf[4], blf[4];
            #pragma unroll
            for (int f = 0; f < 4; ++f) {
                ah[f]  = *(const bf16x8*)(sm +         aoff[f] + col);
                al[f]  = *(const bf16x8*)(sm + 16384 + aoff[f] + col);
                bhf[f] = *(const bf16x8*)(sm + 32768 + boff[f] + col);
                blf[f] = *(const bf16x8*)(sm + 49152 + boff[f] + col);
            }
            #pragma unroll
            for (int i = 0; i < 4; ++i)
                #pragma unroll
                for (int j = 0; j < 4; ++j) {
                    acc[i][j] = __builtin_amdgcn_mfma_f32_16x16x32_bf16(ah[i], bhf[j], acc[i][j], 0, 0, 0);
                    acc[i][j] = __builtin_amdgcn_mfma_f32_16x16x32_bf16(ah[i], blf[j], acc[i][j], 0, 0, 0);
                    acc[i][j] = __builtin_amdgcn_mfma_f32_16x16x32_bf16(al[i], bhf[j], acc[i][j], 0, 0, 0);
                }
        }
        __syncthreads();
    }

    // epilogue: bias + store fp32
    const float* bias = (g == 0) ? bz : (g == 1) ? br : bh;
    const int n0 = nt * 128 + wn * 64;
    const int m0 = mt * 128 + wm * 64;
    float bcol[4];
    #pragma unroll
    for (int f = 0; f < 4; ++f) bcol[f] = bias[n0 + f * 16 + lane15];

    float* cbase = proj + (size_t)g * Mc * U;
    #pragma unroll
    for (int i = 0; i < 4; ++i) {
        #pragma unroll
        for (int jr = 0; jr < 4; ++jr) {
            const int row = m0 + i * 16 + lgrp * 4 + jr;
            float* crow = cbase + (size_t)row * U + n0 + lane15;
            #pragma unroll
            for (int j = 0; j < 4; ++j)
                crow[j * 16] = acc[i][j][jr] + bcol[j];
        }
    }
}

// ---------- scan: one thread per (b,u) ----------
__global__ __launch_bounds__(256)
void bru_scan(const float* __restrict__ proj,  // [3][Mc][U]
              const float* __restrict__ mz, const float* __restrict__ mr,
              float* __restrict__ out,         // [B][T][U]
              float* __restrict__ hstate,      // [B*U]
              int B, int T, int U, int Tc, int t0, int Mc)
{
    const int idx = blockIdx.x * blockDim.x + threadIdx.x;
    const int b = idx / U;
    const int u = idx - b * U;

    float h = (t0 == 0) ? 0.f : hstate[idx];
    const float vmz = mz[u];
    const float vmr = mr[u];

    const float* pz = proj + (long)b * Tc * U + u;
    const float* pr = pz + (long)Mc * U;
    const float* ph = pr + (long)Mc * U;
    float* po = out + ((long)b * T + t0) * U + u;

    float xz = pz[0], xr = pr[0], xh = ph[0];
    for (int t = 0; t < Tc; ++t) {
        float nxz = 0.f, nxr = 0.f, nxh = 0.f;
        if (t + 1 < Tc) {
            const long o = (long)(t + 1) * U;
            nxz = pz[o]; nxr = pr[o]; nxh = ph[o];
        }
        float rr = tanhf(xr + h * vmr) + 1.0f;
        float zz = 1.0f / (1.0f + __expf(-(xz + h * vmz)));
        float hh = tanhf(xh + rr * h);
        h = (1.0f - zz) * hh + zz * h;
        po[(long)t * U] = h;
        xz = nxz; xr = nxr; xh = nxh;
    }
    hstate[idx] = h;
}

// ---------- launch ----------
extern "C" void kernel_launch(void* const* d_in, const int* in_sizes, int n_in,
                              void* d_out, int out_size, void* d_ws, size_t ws_size,
                              hipStream_t stream)
{
    const float* x  = (const float*)d_in[0];
    const float* wz = (const float*)d_in[1];
    const float* wr = (const float*)d_in[2];
    const float* wh = (const float*)d_in[3];
    const float* mz = (const float*)d_in[4];
    const float* mr = (const float*)d_in[5];
    const float* bz = (const float*)d_in[6];
    const float* br = (const float*)d_in[7];
    const float* bh = (const float*)d_in[8];

    const int B = 64, T = 512, D = 1024, U = 1024;
    const int nkt = D / 64;          // 16
    const int nnt = U / 128;         // 8

    // ws layout: [h: 256KB][W blobs: 12.58MB][A blobs][proj fp32]
    const size_t h_bytes = (size_t)B * U * sizeof(float);
    const size_t w_bytes = (size_t)3 * nnt * nkt * 16384 * sizeof(short);

    int Tc = T;
    while (Tc > 4) {
        const int nmt = B * Tc / 128;
        const size_t a_bytes = (size_t)nmt * nkt * 16384 * sizeof(short);
        const size_t p_bytes = 3ull * B * Tc * U * sizeof(float);
        if (h_bytes + w_bytes + a_bytes + p_bytes <= ws_size) break;
        Tc >>= 1;
    }
    const int nmt = B * Tc / 128;
    const int Mc  = B * Tc;
    const size_t a_bytes = (size_t)nmt * nkt * 16384 * sizeof(short);

    float* h_state = (float*)d_ws;
    short* Wblob   = (short*)((char*)d_ws + h_bytes);
    short* Ablob   = (short*)((char*)d_ws + h_bytes + w_bytes);
    float* proj    = (float*)((char*)d_ws + h_bytes + w_bytes + a_bytes);

    // convert weights once
    bru_conv_w<<<(3 * nnt * nkt * 1024) / 256, 256, 0, stream>>>(
        wz, wr, wh, Wblob, D, U, nnt, nkt);

    for (int t0 = 0; t0 < T; t0 += Tc) {
        bru_conv_a<<<(size_t)nmt * nkt * 1024 / 256, 256, 0, stream>>>(
            x, Ablob, T, D, Tc, t0, nkt);

        bru_gemm_mfma<<<3 * nmt * 8, 256, 0, stream>>>(
            Ablob, Wblob, bz, br, bh, proj, nmt, nkt, U, Mc);

        bru_scan<<<(B * U) / 256, 256, 0, stream>>>(
            proj, mz, mr, (float*)d_out, h_state, B, T, U, Tc, t0, Mc);
    }
}

// Round 3
// 875.367 us; speedup vs baseline: 3.0527x; 1.0293x over previous
//
#include <hip/hip_runtime.h>
#include <cmath>

using bf16x8 = __attribute__((ext_vector_type(8))) short;
using f32x4  = __attribute__((ext_vector_type(4))) float;

// ---------- helpers ----------
__device__ __forceinline__ short f2bf_rne(float f) {
    union { float f; unsigned u; } a; a.f = f;
    unsigned r = a.u + 0x7fffu + ((a.u >> 16) & 1u);
    return (short)(r >> 16);
}
__device__ __forceinline__ float bf2f(short s) {
    union { unsigned u; float f; } a;
    a.u = ((unsigned)(unsigned short)s) << 16;
    return a.f;
}
__device__ __forceinline__ void gld16(void* lds, const void* g) {
    __builtin_amdgcn_global_load_lds(
        (const __attribute__((address_space(1))) unsigned int*)g,
        (__attribute__((address_space(3))) unsigned int*)lds, 16, 0, 0);
}

// ================= Blob layout =================
// Per (tile256, kt32): 256 rows x 128B = 32KB.
// Row r, 16B-slot s (0..7): logical slot ls = s ^ (r&7)  [pre-swizzled image]
//   q = ls>>1 (k-octet), isLo = ls&1
//   content: bf16 of elements k = kt*32 + q*8 + j  (hi part, or residual lo part)
// A linear global_load_lds of the blob reproduces this swizzled image in LDS;
// fragment ds_read_b128 at byte ((lgrp<<5)|(isLo<<4)) ^ ((lane&7)<<4) is
// conflict-free (2-way only).

// ---------- convert x -> A blobs ----------
__global__ __launch_bounds__(256)
void bru_conv_a(const float* __restrict__ x, short* __restrict__ Ablob,
                int T, int D, int Tc, int t0)
{
    const int gid  = blockIdx.x * 256 + threadIdx.x;
    const int blob = gid >> 11;           // 2048 16B-groups per blob
    const int idx  = gid & 2047;
    const int row  = idx >> 3;            // 0..255
    const int s    = idx & 7;
    const int mt   = blob >> 5;           // / 32 k-tiles
    const int kt   = blob & 31;

    const int ls   = s ^ (row & 7);
    const int q    = ls >> 1;
    const int isLo = ls & 1;

    const int m = mt * 256 + row;
    const long xrow = (long)(m / Tc) * T + t0 + (m % Tc);
    const float* src = x + xrow * (long)D + kt * 32 + q * 8;

    float v[8];
    *(float4*)&v[0] = *(const float4*)(src);
    *(float4*)&v[4] = *(const float4*)(src + 4);

    short o[8];
    #pragma unroll
    for (int j = 0; j < 8; ++j) {
        short h = f2bf_rne(v[j]);
        o[j] = isLo ? f2bf_rne(v[j] - bf2f(h)) : h;
    }
    *(bf16x8*)(Ablob + (size_t)blob * 16384 + row * 64 + s * 8) = *(bf16x8*)o;
}

// ---------- convert W (3 gates) -> B blobs (rows = u, k-contig) ----------
__global__ __launch_bounds__(256)
void bru_conv_w(const float* __restrict__ wz, const float* __restrict__ wr,
                const float* __restrict__ wh, short* __restrict__ Wblob,
                int D, int U)
{
    const int gid  = blockIdx.x * 256 + threadIdx.x;
    const int blob = gid >> 11;
    const int idx  = gid & 2047;
    const int row  = idx >> 3;            // u within 256-col tile
    const int s    = idx & 7;

    const int g    = blob >> 7;           // 4 nt * 32 kt = 128 blobs/gate
    const int rest = blob & 127;
    const int nt   = rest >> 5;
    const int kt   = rest & 31;

    const int ls   = s ^ (row & 7);
    const int q    = ls >> 1;
    const int isLo = ls & 1;

    const float* W = (g == 0) ? wz : (g == 1) ? wr : wh;
    const int d0 = kt * 32 + q * 8;
    const int u  = nt * 256 + row;

    short o[8];
    #pragma unroll
    for (int j = 0; j < 8; ++j) {
        float v = W[(long)(d0 + j) * U + u];
        short h = f2bf_rne(v);
        o[j] = isLo ? f2bf_rne(v - bf2f(h)) : h;
    }
    *(bf16x8*)(Wblob + (size_t)blob * 16384 + row * 64 + s * 8) = *(bf16x8*)o;
}

// ---------- split-precision bf16 MFMA GEMM, 256x256 tile, 8-phase-style ----------
// C[g][m][u] = sum_d A[m][d]*W_g[d][u] + bias_g[u]  via hi*hi + hi*lo + lo*hi
__global__ __launch_bounds__(512, 2)
void bru_gemm_mfma(const short* __restrict__ Ablob, const short* __restrict__ Wblob,
                   const float* __restrict__ bz, const float* __restrict__ br,
                   const float* __restrict__ bh,
                   _Float16* __restrict__ proj,
                   int nmt, int U, int Mc)
{
    __shared__ char sm[131072];  // [2 buf][A 32KB | B 32KB]

    const int ngrid = gridDim.x;
    const int bid   = blockIdx.x;
    int lid = bid;
    if ((ngrid & 7) == 0) lid = (bid & 7) * (ngrid >> 3) + (bid >> 3);
    const int per_gate = nmt * 4;
    const int g  = lid / per_gate;
    const int r  = lid - g * per_gate;
    const int mt = r >> 2;                // mt-major: 4 consecutive blocks share A
    const int nt = r & 3;

    const int tid    = threadIdx.x;
    const int w      = tid >> 6;
    const int lane   = tid & 63;
    const int wm     = w >> 2, wn = w & 3;     // 2x4 wave grid; wave tile 128x64
    const int lane15 = lane & 15;
    const int lgrp   = lane >> 4;
    const int swz    = (lane & 7) << 4;
    const int hioff  = (lgrp << 5) ^ swz;      // lo at hioff ^ 16

    const char* asrc = (const char*)Ablob + (size_t)(mt * 32) * 32768;
    const char* bsrc = (const char*)Wblob + (size_t)((g * 4 + nt) * 32) * 32768;

    // per-thread LDS read bases
    const int abase = wm * 16384 + lane15 * 128 + hioff;          // + p*4096, +2048 for 2nd m-frag
    const int bbase = 32768 + wn * 8192 + lane15 * 128 + hioff;   // + j*2048
    const int stoff = tid * 16;                                   // staging offset

    f32x4 acc[8][4];
    #pragma unroll
    for (int i = 0; i < 8; ++i)
        #pragma unroll
        for (int j = 0; j < 4; ++j) acc[i][j] = (f32x4)0.f;

    // prologue: stage kt=0 into buf0
    #pragma unroll
    for (int i = 0; i < 4; ++i) {
        gld16(sm + i * 8192 + stoff,         asrc + i * 8192 + stoff);
        gld16(sm + 32768 + i * 8192 + stoff, bsrc + i * 8192 + stoff);
    }
    asm volatile("s_waitcnt vmcnt(0)" ::: "memory");
    __builtin_amdgcn_s_barrier();

    for (int kt = 0; kt < 32; ++kt) {
        const int cb = (kt & 1) << 16;
        const int nb = cb ^ 65536;
        const char* smc = sm + cb;
        const char* abn = asrc + (size_t)(kt + 1) * 32768;
        const char* bbn = bsrc + (size_t)(kt + 1) * 32768;
        const bool pf = (kt < 31);

        bf16x8 bhf[4], blf[4];

        #pragma unroll
        for (int p = 0; p < 4; ++p) {
            // ds reads for this phase: A m-frags 2p, 2p+1 (hi+lo)
            const char* ap = smc + abase + p * 4096;
            bf16x8 ah0 = *(const bf16x8*)(ap);
            bf16x8 al0 = *(const bf16x8*)(smc + ((abase + p * 4096) ^ 16));
            bf16x8 ah1 = *(const bf16x8*)(ap + 2048);
            bf16x8 al1 = *(const bf16x8*)(smc + ((abase + p * 4096 + 2048) ^ 16));
            if (p == 0) {
                #pragma unroll
                for (int j = 0; j < 4; ++j) {
                    bhf[j] = *(const bf16x8*)(smc + bbase + j * 2048);
                    blf[j] = *(const bf16x8*)(smc + ((bbase + j * 2048) ^ 16));
                }
            }
            // prefetch next K-tile: 2 gld16 per phase (8 total per K-tile)
            if (pf) {
                gld16(sm + nb + p * 8192 + stoff,         abn + p * 8192 + stoff);
                gld16(sm + nb + 32768 + p * 8192 + stoff, bbn + p * 8192 + stoff);
            }
            __builtin_amdgcn_s_barrier();
            asm volatile("s_waitcnt lgkmcnt(0)" ::: "memory");
            __builtin_amdgcn_sched_barrier(0);
            __builtin_amdgcn_s_setprio(1);
            #pragma unroll
            for (int j = 0; j < 4; ++j) {
                acc[2*p  ][j] = __builtin_amdgcn_mfma_f32_16x16x32_bf16(ah0, bhf[j], acc[2*p  ][j], 0, 0, 0);
                acc[2*p  ][j] = __builtin_amdgcn_mfma_f32_16x16x32_bf16(ah0, blf[j], acc[2*p  ][j], 0, 0, 0);
                acc[2*p  ][j] = __builtin_amdgcn_mfma_f32_16x16x32_bf16(al0, bhf[j], acc[2*p  ][j], 0, 0, 0);
                acc[2*p+1][j] = __builtin_amdgcn_mfma_f32_16x16x32_bf16(ah1, bhf[j], acc[2*p+1][j], 0, 0, 0);
                acc[2*p+1][j] = __builtin_amdgcn_mfma_f32_16x16x32_bf16(ah1, blf[j], acc[2*p+1][j], 0, 0, 0);
                acc[2*p+1][j] = __builtin_amdgcn_mfma_f32_16x16x32_bf16(al1, bhf[j], acc[2*p+1][j], 0, 0, 0);
            }
            __builtin_amdgcn_s_setprio(0);
            if (p == 3) asm volatile("s_waitcnt vmcnt(0)" ::: "memory");
            __builtin_amdgcn_s_barrier();
        }
    }

    // epilogue: bias + f16 store
    const float* bias = (g == 0) ? bz : (g == 1) ? br : bh;
    const int n0 = nt * 256 + wn * 64;
    const int m0 = mt * 256 + wm * 128;
    float bcol[4];
    #pragma unroll
    for (int j = 0; j < 4; ++j) bcol[j] = bias[n0 + j * 16 + lane15];

    _Float16* cbase = proj + (size_t)g * Mc * U;
    #pragma unroll
    for (int i = 0; i < 8; ++i) {
        #pragma unroll
        for (int jr = 0; jr < 4; ++jr) {
            const int row = m0 + i * 16 + lgrp * 4 + jr;
            _Float16* crow = cbase + (size_t)row * U + n0 + lane15;
            #pragma unroll
            for (int j = 0; j < 4; ++j)
                crow[j * 16] = (_Float16)(acc[i][j][jr] + bcol[j]);
        }
    }
}

// ---------- scan: one thread per (b,u) ----------
__global__ __launch_bounds__(256)
void bru_scan(const _Float16* __restrict__ proj,  // [3][Mc][U]
              const float* __restrict__ mz, const float* __restrict__ mr,
              float* __restrict__ out,            // [B][T][U]
              float* __restrict__ hstate,         // [B*U]
              int B, int T, int U, int Tc, int t0, int Mc)
{
    const int idx = blockIdx.x * blockDim.x + threadIdx.x;
    const int b = idx / U;
    const int u = idx - b * U;

    float h = (t0 == 0) ? 0.f : hstate[idx];
    const float vmz = mz[u];
    const float vmr = mr[u];

    const _Float16* pz = proj + (long)b * Tc * U + u;
    const _Float16* pr = pz + (long)Mc * U;
    const _Float16* ph = pr + (long)Mc * U;
    float* po = out + ((long)b * T + t0) * U + u;

    float xz = (float)pz[0], xr = (float)pr[0], xh = (float)ph[0];
    for (int t = 0; t < Tc; ++t) {
        float nxz = 0.f, nxr = 0.f, nxh = 0.f;
        if (t + 1 < Tc) {
            const long o = (long)(t + 1) * U;
            nxz = (float)pz[o]; nxr = (float)pr[o]; nxh = (float)ph[o];
        }
        float rr = tanhf(xr + h * vmr) + 1.0f;
        float zz = 1.0f / (1.0f + __expf(-(xz + h * vmz)));
        float hh = tanhf(xh + rr * h);
        h = (1.0f - zz) * hh + zz * h;
        po[(long)t * U] = h;
        xz = nxz; xr = nxr; xh = nxh;
    }
    hstate[idx] = h;
}

// ---------- launch ----------
extern "C" void kernel_launch(void* const* d_in, const int* in_sizes, int n_in,
                              void* d_out, int out_size, void* d_ws, size_t ws_size,
                              hipStream_t stream)
{
    const float* x  = (const float*)d_in[0];
    const float* wz = (const float*)d_in[1];
    const float* wr = (const float*)d_in[2];
    const float* wh = (const float*)d_in[3];
    const float* mz = (const float*)d_in[4];
    const float* mr = (const float*)d_in[5];
    const float* bz = (const float*)d_in[6];
    const float* br = (const float*)d_in[7];
    const float* bh = (const float*)d_in[8];

    const int B = 64, T = 512, D = 1024, U = 1024;

    const size_t h_bytes = (size_t)B * U * sizeof(float);
    const size_t w_bytes = (size_t)3 * 4 * 32 * 16384 * sizeof(short);  // 12.58 MB

    int Tc = T;
    while (Tc > 4) {
        const int nmt_ = B * Tc / 256;
        const size_t a_bytes_ = (size_t)nmt_ * 32 * 16384 * sizeof(short);
        const size_t p_bytes_ = 3ull * B * Tc * U * sizeof(_Float16);
        if (h_bytes + w_bytes + a_bytes_ + p_bytes_ <= ws_size) break;
        Tc >>= 1;
    }
    const int nmt = B * Tc / 256;
    const int Mc  = B * Tc;
    const size_t a_bytes = (size_t)nmt * 32 * 16384 * sizeof(short);

    float*    h_state = (float*)d_ws;
    short*    Wblob   = (short*)((char*)d_ws + h_bytes);
    short*    Ablob   = (short*)((char*)d_ws + h_bytes + w_bytes);
    _Float16* proj    = (_Float16*)((char*)d_ws + h_bytes + w_bytes + a_bytes);

    // convert weights once
    bru_conv_w<<<3 * 4 * 32 * 2048 / 256, 256, 0, stream>>>(wz, wr, wh, Wblob, D, U);

    for (int t0 = 0; t0 < T; t0 += Tc) {
        bru_conv_a<<<nmt * 32 * 2048 / 256, 256, 0, stream>>>(x, Ablob, T, D, Tc, t0);

        bru_gemm_mfma<<<3 * nmt * 4, 512, 0, stream>>>(
            Ablob, Wblob, bz, br, bh, proj, nmt, U, Mc);

        bru_scan<<<(B * U) / 256, 256, 0, stream>>>(
            proj, mz, mr, (float*)d_out, h_state, B, T, U, Tc, t0, Mc);
    }
}

// Round 4
// 663.726 us; speedup vs baseline: 4.0262x; 1.3189x over previous
//
#include <hip/hip_runtime.h>
#include <cmath>

using bf16x8 = __attribute__((ext_vector_type(8))) short;
using f32x4  = __attribute__((ext_vector_type(4))) float;

// ---------- helpers ----------
__device__ __forceinline__ short f2bf_rne(float f) {
    union { float f; unsigned u; } a; a.f = f;
    unsigned r = a.u + 0x7fffu + ((a.u >> 16) & 1u);
    return (short)(r >> 16);
}
__device__ __forceinline__ float bf2f(short s) {
    union { unsigned u; float f; } a;
    a.u = ((unsigned)(unsigned short)s) << 16;
    return a.f;
}
__device__ __forceinline__ void gld16(void* lds, const void* g) {
    __builtin_amdgcn_global_load_lds(
        (const __attribute__((address_space(1))) unsigned int*)g,
        (__attribute__((address_space(3))) unsigned int*)lds, 16, 0, 0);
}

// ================= Blob layout =================
// Per (tile256, kt32): 256 rows x 128B = 32KB.
// Row r, 16B-slot s: logical slot ls = s ^ (r&7); q = ls>>1, isLo = ls&1;
// content = bf16 hi/lo of elements k = kt*32 + q*8 + j.
// Linear global_load_lds reproduces the swizzled image; fragment ds_read_b128
// at byte ((lgrp<<5)|(isLo<<4)) ^ ((lane&7)<<4) is conflict-free.

// ---------- convert x -> A blobs (each thread: one k-octet, hi AND lo) ----------
__global__ __launch_bounds__(256)
void bru_conv_a(const float* __restrict__ x, short* __restrict__ Ablob,
                int T, int D, int Tc, int t0)
{
    const int gid  = blockIdx.x * 256 + threadIdx.x;
    const int blob = gid >> 10;           // 1024 threads per blob (256 rows x 4 octets)
    const int idx  = gid & 1023;
    const int row  = idx >> 2;
    const int q    = idx & 3;
    const int mt   = blob >> 5;
    const int kt   = blob & 31;

    const int m = mt * 256 + row;
    const long xrow = (long)(m / Tc) * T + t0 + (m % Tc);
    const float* src = x + xrow * (long)D + kt * 32 + q * 8;

    float v[8];
    *(float4*)&v[0] = *(const float4*)(src);
    *(float4*)&v[4] = *(const float4*)(src + 4);

    short hi[8], lo[8];
    #pragma unroll
    for (int j = 0; j < 8; ++j) {
        hi[j] = f2bf_rne(v[j]);
        lo[j] = f2bf_rne(v[j] - bf2f(hi[j]));
    }
    short* base = Ablob + (size_t)blob * 16384 + row * 64;
    const int sh = (2 * q) ^ (row & 7);
    *(bf16x8*)(base + sh * 8)       = *(bf16x8*)hi;
    *(bf16x8*)(base + (sh ^ 1) * 8) = *(bf16x8*)lo;
}

// ---------- convert W (3 gates) -> B blobs (rows = u, k-contig) ----------
__global__ __launch_bounds__(256)
void bru_conv_w(const float* __restrict__ wz, const float* __restrict__ wr,
                const float* __restrict__ wh, short* __restrict__ Wblob,
                int D, int U)
{
    const int gid  = blockIdx.x * 256 + threadIdx.x;
    const int blob = gid >> 10;
    const int idx  = gid & 1023;
    const int row  = idx >> 2;            // u within 256-col tile
    const int q    = idx & 3;

    const int g    = blob >> 7;           // 4 nt * 32 kt = 128 blobs/gate
    const int rest = blob & 127;
    const int nt   = rest >> 5;
    const int kt   = rest & 31;

    const float* W = (g == 0) ? wz : (g == 1) ? wr : wh;
    const int d0 = kt * 32 + q * 8;
    const int u  = nt * 256 + row;

    short hi[8], lo[8];
    #pragma unroll
    for (int j = 0; j < 8; ++j) {
        float v = W[(long)(d0 + j) * U + u];
        hi[j] = f2bf_rne(v);
        lo[j] = f2bf_rne(v - bf2f(hi[j]));
    }
    short* base = Wblob + (size_t)blob * 16384 + row * 64;
    const int sh = (2 * q) ^ (row & 7);
    *(bf16x8*)(base + sh * 8)       = *(bf16x8*)hi;
    *(bf16x8*)(base + (sh ^ 1) * 8) = *(bf16x8*)lo;
}

// ---------- split-precision bf16 MFMA GEMM, 256x256 tile ----------
// C[g][m][u] = sum_d A[m][d]*W_g[d][u] + bias_g[u]  via hi*hi + hi*lo + lo*hi
__global__ __launch_bounds__(512, 2)
void bru_gemm_mfma(const short* __restrict__ Ablob, const short* __restrict__ Wblob,
                   const float* __restrict__ bz, const float* __restrict__ br,
                   const float* __restrict__ bh,
                   _Float16* __restrict__ proj,
                   int nmt, int U, int Mc)
{
    __shared__ char sm[131072];  // [2 buf][A 32KB | B 32KB]

    const int ngrid = gridDim.x;
    const int bid   = blockIdx.x;
    int lid = bid;
    if ((ngrid & 7) == 0) lid = (bid & 7) * (ngrid >> 3) + (bid >> 3);
    const int per_gate = nmt * 4;
    const int g  = lid / per_gate;
    const int r  = lid - g * per_gate;
    const int mt = r >> 2;                // mt-major: 4 consecutive blocks share A
    const int nt = r & 3;

    const int tid    = threadIdx.x;
    const int w      = tid >> 6;
    const int lane   = tid & 63;
    const int wm     = w >> 2, wn = w & 3;     // 2x4 wave grid; wave tile 128x64
    const int lane15 = lane & 15;
    const int lgrp   = lane >> 4;
    const int swz    = (lane & 7) << 4;
    const int hioff  = (lgrp << 5) ^ swz;      // lo at hioff ^ 16

    const char* asrc = (const char*)Ablob + (size_t)(mt * 32) * 32768;
    const char* bsrc = (const char*)Wblob + (size_t)((g * 4 + nt) * 32) * 32768;

    const int abase = wm * 16384 + lane15 * 128 + hioff;          // + p*4096, +2048 for 2nd m-frag
    const int bbase = 32768 + wn * 8192 + lane15 * 128 + hioff;   // + j*2048
    const int stoff = tid * 16;

    f32x4 acc[8][4];
    #pragma unroll
    for (int i = 0; i < 8; ++i)
        #pragma unroll
        for (int j = 0; j < 4; ++j) acc[i][j] = (f32x4)0.f;

    // prologue: stage kt=0 into buf0
    #pragma unroll
    for (int i = 0; i < 4; ++i) {
        gld16(sm + i * 8192 + stoff,         asrc + i * 8192 + stoff);
        gld16(sm + 32768 + i * 8192 + stoff, bsrc + i * 8192 + stoff);
    }
    asm volatile("s_waitcnt vmcnt(0)" ::: "memory");
    __builtin_amdgcn_s_barrier();

    for (int kt = 0; kt < 32; ++kt) {
        const int cb = (kt & 1) << 16;
        const int nb = cb ^ 65536;
        const char* smc = sm + cb;
        const char* abn = asrc + (size_t)(kt + 1) * 32768;
        const char* bbn = bsrc + (size_t)(kt + 1) * 32768;
        const bool pf = (kt < 31);

        bf16x8 bhf[4], blf[4];

        #pragma unroll
        for (int p = 0; p < 4; ++p) {
            // ds reads for this phase: A m-frags 2p, 2p+1 (hi+lo)
            const char* ap = smc + abase + p * 4096;
            bf16x8 ah0 = *(const bf16x8*)(ap);
            bf16x8 al0 = *(const bf16x8*)(smc + ((abase + p * 4096) ^ 16));
            bf16x8 ah1 = *(const bf16x8*)(ap + 2048);
            bf16x8 al1 = *(const bf16x8*)(smc + ((abase + p * 4096 + 2048) ^ 16));
            if (p == 0) {
                #pragma unroll
                for (int j = 0; j < 4; ++j) {
                    bhf[j] = *(const bf16x8*)(smc + bbase + j * 2048);
                    blf[j] = *(const bf16x8*)(smc + ((bbase + j * 2048) ^ 16));
                }
                // cluster ALL next-tile prefetch here: ~3 phases to land
                if (pf) {
                    #pragma unroll
                    for (int i = 0; i < 4; ++i) {
                        gld16(sm + nb + i * 8192 + stoff,         abn + i * 8192 + stoff);
                        gld16(sm + nb + 32768 + i * 8192 + stoff, bbn + i * 8192 + stoff);
                    }
                }
            }
            __builtin_amdgcn_s_barrier();
            asm volatile("s_waitcnt lgkmcnt(0)" ::: "memory");
            __builtin_amdgcn_sched_barrier(0);
            __builtin_amdgcn_s_setprio(1);
            #pragma unroll
            for (int j = 0; j < 4; ++j) {
                acc[2*p  ][j] = __builtin_amdgcn_mfma_f32_16x16x32_bf16(ah0, bhf[j], acc[2*p  ][j], 0, 0, 0);
                acc[2*p  ][j] = __builtin_amdgcn_mfma_f32_16x16x32_bf16(ah0, blf[j], acc[2*p  ][j], 0, 0, 0);
                acc[2*p  ][j] = __builtin_amdgcn_mfma_f32_16x16x32_bf16(al0, bhf[j], acc[2*p  ][j], 0, 0, 0);
                acc[2*p+1][j] = __builtin_amdgcn_mfma_f32_16x16x32_bf16(ah1, bhf[j], acc[2*p+1][j], 0, 0, 0);
                acc[2*p+1][j] = __builtin_amdgcn_mfma_f32_16x16x32_bf16(ah1, blf[j], acc[2*p+1][j], 0, 0, 0);
                acc[2*p+1][j] = __builtin_amdgcn_mfma_f32_16x16x32_bf16(al1, bhf[j], acc[2*p+1][j], 0, 0, 0);
            }
            __builtin_amdgcn_s_setprio(0);
            if (p == 3) asm volatile("s_waitcnt vmcnt(0)" ::: "memory");  // waits on loads issued at p==0
            __builtin_amdgcn_s_barrier();
        }
    }

    // epilogue: bias + f16 store
    const float* bias = (g == 0) ? bz : (g == 1) ? br : bh;
    const int n0 = nt * 256 + wn * 64;
    const int m0 = mt * 256 + wm * 128;
    float bcol[4];
    #pragma unroll
    for (int j = 0; j < 4; ++j) bcol[j] = bias[n0 + j * 16 + lane15];

    _Float16* cbase = proj + (size_t)g * Mc * U;
    #pragma unroll
    for (int i = 0; i < 8; ++i) {
        #pragma unroll
        for (int jr = 0; jr < 4; ++jr) {
            const int row = m0 + i * 16 + lgrp * 4 + jr;
            _Float16* crow = cbase + (size_t)row * U + n0 + lane15;
            #pragma unroll
            for (int j = 0; j < 4; ++j)
                crow[j * 16] = (_Float16)(acc[i][j][jr] + bcol[j]);
        }
    }
}

// ---------- scan: one thread per (b,u); 8-deep rotating register prefetch ----------
#define PF 8
__global__ __launch_bounds__(256)
void bru_scan(const _Float16* __restrict__ proj,  // [3][Mc][U]
              const float* __restrict__ mz, const float* __restrict__ mr,
              float* __restrict__ out,            // [B][T][U]
              float* __restrict__ hstate,         // [B*U]
              int B, int T, int U, int Tc, int t0, int Mc)
{
    const int idx = blockIdx.x * blockDim.x + threadIdx.x;
    const int b = idx / U;
    const int u = idx - b * U;

    float h = (t0 == 0) ? 0.f : hstate[idx];
    const float vmz = mz[u];
    const float vmr = mr[u];

    const _Float16* pz = proj + (long)b * Tc * U + u;
    const _Float16* pr = pz + (long)Mc * U;
    const _Float16* ph = pr + (long)Mc * U;
    float* po = out + ((long)b * T + t0) * U + u;

    _Float16 fz[PF], fr[PF], fh[PF];
    #pragma unroll
    for (int i = 0; i < PF; ++i) {
        const long o = (long)((i < Tc) ? i : (Tc - 1)) * U;
        fz[i] = pz[o]; fr[i] = pr[o]; fh[i] = ph[o];
    }

    for (int t = 0; t < Tc; t += PF) {
        #pragma unroll
        for (int i = 0; i < PF; ++i) {
            const float xz = (float)fz[i];
            const float xr = (float)fr[i];
            const float xh = (float)fh[i];
            // refill slot i with time t+i+PF (clamped)
            {
                int tn = t + i + PF; if (tn > Tc - 1) tn = Tc - 1;
                const long o = (long)tn * U;
                fz[i] = pz[o]; fr[i] = pr[o]; fh[i] = ph[o];
            }
            // tanh via exp2-backed __expf: tanh(x)+c forms, saturate correctly at +-inf
            const float e2r = __expf(2.f * (xr + h * vmr));
            const float rr  = 2.f - 2.f / (e2r + 1.f);            // tanh(.)+1
            const float zz  = 1.f / (1.f + __expf(-(xz + h * vmz)));
            const float e2h = __expf(2.f * (xh + rr * h));
            const float hh  = 1.f - 2.f / (e2h + 1.f);             // tanh(.)
            h = (1.f - zz) * hh + zz * h;
            if (t + i < Tc) po[(long)(t + i) * U] = h;
        }
    }
    hstate[idx] = h;
}

// ---------- launch ----------
extern "C" void kernel_launch(void* const* d_in, const int* in_sizes, int n_in,
                              void* d_out, int out_size, void* d_ws, size_t ws_size,
                              hipStream_t stream)
{
    const float* x  = (const float*)d_in[0];
    const float* wz = (const float*)d_in[1];
    const float* wr = (const float*)d_in[2];
    const float* wh = (const float*)d_in[3];
    const float* mz = (const float*)d_in[4];
    const float* mr = (const float*)d_in[5];
    const float* bz = (const float*)d_in[6];
    const float* br = (const float*)d_in[7];
    const float* bh = (const float*)d_in[8];

    const int B = 64, T = 512, D = 1024, U = 1024;

    const size_t h_bytes = (size_t)B * U * sizeof(float);
    const size_t w_bytes = (size_t)3 * 4 * 32 * 16384 * sizeof(short);  // 12.58 MB

    int Tc = T;
    while (Tc > 4) {
        const int nmt_ = B * Tc / 256;
        const size_t a_bytes_ = (size_t)nmt_ * 32 * 16384 * sizeof(short);
        const size_t p_bytes_ = 3ull * B * Tc * U * sizeof(_Float16);
        if (h_bytes + w_bytes + a_bytes_ + p_bytes_ <= ws_size) break;
        Tc >>= 1;
    }
    const int nmt = B * Tc / 256;
    const int Mc  = B * Tc;
    const size_t a_bytes = (size_t)nmt * 32 * 16384 * sizeof(short);

    float*    h_state = (float*)d_ws;
    short*    Wblob   = (short*)((char*)d_ws + h_bytes);
    short*    Ablob   = (short*)((char*)d_ws + h_bytes + w_bytes);
    _Float16* proj    = (_Float16*)((char*)d_ws + h_bytes + w_bytes + a_bytes);

    // convert weights once
    bru_conv_w<<<3 * 4 * 32 * 1024 / 256, 256, 0, stream>>>(wz, wr, wh, Wblob, D, U);

    for (int t0 = 0; t0 < T; t0 += Tc) {
        bru_conv_a<<<nmt * 32 * 1024 / 256, 256, 0, stream>>>(x, Ablob, T, D, Tc, t0);

        bru_gemm_mfma<<<3 * nmt * 4, 512, 0, stream>>>(
            Ablob, Wblob, bz, br, bh, proj, nmt, U, Mc);

        bru_scan<<<(B * U) / 256, 256, 0, stream>>>(
            proj, mz, mr, (float*)d_out, h_state, B, T, U, Tc, t0, Mc);
    }
}